// Round 6
// baseline (1383.197 us; speedup 1.0000x reference)
//
#include <hip/hip_runtime.h>
#include <stdint.h>

#define N 8192
#define D 256          // elements per row == bytes per fp8 row
#define INV_T 20.0f
#define BM 128
#define BN 128
#define BK 64
#define NXB 64         // col-blocks (N/BN)

typedef __attribute__((ext_vector_type(16))) float f32x16;
typedef __attribute__((ext_vector_type(2))) long i64x2;

typedef __attribute__((address_space(3))) uint32_t lds_u32;
typedef __attribute__((address_space(1))) const uint32_t gbl_u32;

// Kernel 1: per-row fp32 normalize -> fp8 e4m3 (OCP) copies; c[i]=(e_i.p_i)/T exact fp32.
// Also zeroes out[0] (poisoned 0xAA; reduce kernel atomicAdds into it).
__global__ __launch_bounds__(256) void normalize_kernel(
    const float* __restrict__ e, const float* __restrict__ p, const float* __restrict__ n,
    uint32_t* __restrict__ eb, uint32_t* __restrict__ pb, uint32_t* __restrict__ nb,
    float* __restrict__ cbuf, float* __restrict__ out0) {
  const int tid = threadIdx.x;
  const int wave = tid >> 6, lane = tid & 63;
  const int row = blockIdx.x * 4 + wave;          // one wave per row
  if (blockIdx.x == 0 && tid == 0) out0[0] = 0.0f;

  const float4 ev = ((const float4*)(e + (size_t)row * D))[lane];
  const float4 pv = ((const float4*)(p + (size_t)row * D))[lane];
  const float4 nv = ((const float4*)(n + (size_t)row * D))[lane];

  float sse = ev.x*ev.x + ev.y*ev.y + ev.z*ev.z + ev.w*ev.w;
  float ssp = pv.x*pv.x + pv.y*pv.y + pv.z*pv.z + pv.w*pv.w;
  float ssn = nv.x*nv.x + nv.y*nv.y + nv.z*nv.z + nv.w*nv.w;
  float dep = ev.x*pv.x + ev.y*pv.y + ev.z*pv.z + ev.w*pv.w;
#pragma unroll
  for (int m = 1; m < 64; m <<= 1) {
    sse += __shfl_xor(sse, m);
    ssp += __shfl_xor(ssp, m);
    ssn += __shfl_xor(ssn, m);
    dep += __shfl_xor(dep, m);
  }
  const float se = 1.0f / fmaxf(sqrtf(sse), 1e-8f);
  const float sp = 1.0f / fmaxf(sqrtf(ssp), 1e-8f);
  const float sn = 1.0f / fmaxf(sqrtf(ssn), 1e-8f);

  int ue = __builtin_amdgcn_cvt_pk_fp8_f32(ev.x*se, ev.y*se, 0, false);
  ue     = __builtin_amdgcn_cvt_pk_fp8_f32(ev.z*se, ev.w*se, ue, true);
  int up = __builtin_amdgcn_cvt_pk_fp8_f32(pv.x*sp, pv.y*sp, 0, false);
  up     = __builtin_amdgcn_cvt_pk_fp8_f32(pv.z*sp, pv.w*sp, up, true);
  int un = __builtin_amdgcn_cvt_pk_fp8_f32(nv.x*sn, nv.y*sn, 0, false);
  un     = __builtin_amdgcn_cvt_pk_fp8_f32(nv.z*sn, nv.w*sn, un, true);
  eb[row * 64 + lane] = (uint32_t)ue;
  pb[row * 64 + lane] = (uint32_t)up;
  nb[row * 64 + lane] = (uint32_t)un;

  if (lane == 0) cbuf[row] = dep * se * sp * INV_T;
}

// Kernel 2: 128x128-tile fp8 GEMM (X @ Y^T), 32x32x16_fp8_fp8 MFMA, fused exp row-sums.
// Round-3 structure (BK=64, 4 pipelined k-iters) with the occupancy cap raised:
// __launch_bounds__(256,8) -> 8 blocks/CU (VGPR 48<=64, LDS 8*16.9KB<=160KB), so
// resident blocks hide each other's vmcnt(0)+barrier drains (m114 pipe overlap).
// LDS swizzle: 16B-group gg of row r at slot gg ^ ((r>>1)&3): conflict-free b128 reads;
// storage-only K-permutation applied identically to A and B.
__global__ __launch_bounds__(256, 8) void simexp_kernel(
    const uint8_t* __restrict__ eb, const uint8_t* __restrict__ pb,
    const uint8_t* __restrict__ nb, const float* __restrict__ cbuf,
    float* __restrict__ part) {
  __shared__ uint8_t As[BM * BK];   // 8 KB
  __shared__ uint8_t Bs[BN * BK];   // 8 KB
  __shared__ float cs[BM];          // 512 B

  const int z = blockIdx.z;
  const uint8_t* __restrict__ A = z ? pb : eb;
  const uint8_t* __restrict__ B = z ? eb : nb;

  const int tid = threadIdx.x;
  const int wave = tid >> 6, lane = tid & 63;
  const int lane31 = lane & 31, half = lane >> 5;
  const int rowTile = blockIdx.x * BM, colblk = blockIdx.y;
  const int colTile = colblk * BN;
  const int rl = wave * 32 + lane31;              // this lane's A row (local)

  if (tid < BM) cs[tid] = cbuf[rowTile + tid];

  f32x16 acc[4];
#pragma unroll
  for (int ni = 0; ni < 4; ++ni)
#pragma unroll
    for (int r = 0; r < 16; ++r) acc[ni][r] = 0.0f;

#pragma unroll
  for (int k0i = 0; k0i < 4; ++k0i) {
    const int k0 = k0i * BK;
    __syncthreads();   // LDS reuse guard (publishes cs on iter 0)
#pragma unroll
    for (int t = 0; t < 2; ++t) {                 // A: 128x64B = 512 16B-chunks
      const int c = t * 256 + tid;
      const int r = c >> 2, sl = c & 3;
      const int gg = sl ^ ((r >> 1) & 3);         // swizzled SOURCE group
      __builtin_amdgcn_global_load_lds(
          (gbl_u32*)(A + (size_t)(rowTile + r) * D + k0 + gg * 16),
          (lds_u32*)&As[c * 16], 16, 0, 0);
    }
#pragma unroll
    for (int t = 0; t < 2; ++t) {                 // B: 512 16B-chunks
      const int c = t * 256 + tid;
      const int r = c >> 2, sl = c & 3;
      const int gg = sl ^ ((r >> 1) & 3);
      __builtin_amdgcn_global_load_lds(
          (gbl_u32*)(B + (size_t)(colTile + r) * D + k0 + gg * 16),
          (lds_u32*)&Bs[c * 16], 16, 0, 0);
    }
    __syncthreads();   // drain -> tiles visible

#pragma unroll
    for (int g = 0; g < 2; ++g) {
      const int gga = half * 2 + g;               // this lane's logical 16B-group
      const i64x2 av = *(const i64x2*)&As[rl * BK + ((gga ^ ((rl >> 1) & 3)) * 16)];
      i64x2 bv[4];
#pragma unroll
      for (int ni = 0; ni < 4; ++ni) {
        const int cl = ni * 32 + lane31;
        bv[ni] = *(const i64x2*)&Bs[cl * BK + ((gga ^ ((cl >> 1) & 3)) * 16)];
      }
#pragma unroll
      for (int ni = 0; ni < 4; ++ni)
        acc[ni] = __builtin_amdgcn_mfma_f32_32x32x16_fp8_fp8(av.x, bv[ni].x, acc[ni], 0, 0, 0);
#pragma unroll
      for (int ni = 0; ni < 4; ++ni)
        acc[ni] = __builtin_amdgcn_mfma_f32_32x32x16_fp8_fp8(av.y, bv[ni].y, acc[ni], 0, 0, 0);
    }
  }

  // Epilogue. 32x32 C/D: col=lane&31, row=(reg&3)+8*(reg>>2)+4*half (m74/m101).
#pragma unroll
  for (int reg = 0; reg < 16; ++reg) {
    const int rlocal = (reg & 3) + 8 * (reg >> 2) + 4 * half;
    const int rowl = wave * 32 + rlocal;
    const float cv = cs[rowl];
    float v = 0.0f;
#pragma unroll
    for (int ni = 0; ni < 4; ++ni)
      v += __expf(acc[ni][reg] * INV_T - cv);
    v += __shfl_xor(v, 1);
    v += __shfl_xor(v, 2);
    v += __shfl_xor(v, 4);
    v += __shfl_xor(v, 8);
    v += __shfl_xor(v, 16);
    if (lane31 == 0)
      part[((size_t)(z * NXB + colblk)) * N + rowTile + rowl] = v;
  }
}

// Kernel 3: per-row sum of 64 partials -> log/log1p -> block reduce -> atomicAdd(out).
// 256 blocks; block handles 64 row-items; (tid&63)=item, (tid>>6)=quarter of x-range.
__global__ __launch_bounds__(256) void reduce_kernel(const float* __restrict__ part,
                                                     float* __restrict__ out) {
  __shared__ float sm[64][4];
  const int tid = threadIdx.x;
  const int item0 = blockIdx.x * 64;               // items: z*N + row, 16384 total
  const int il = tid & 63, seg = tid >> 6;
  const int item = item0 + il;
  const int z = item >> 13, row = item & (N - 1);
  float s = 0.0f;
#pragma unroll
  for (int x = seg * 16; x < seg * 16 + 16; ++x)
    s += part[((size_t)(z * NXB + x)) * N + row];
  sm[il][seg] = s;
  __syncthreads();
  if (tid < 64) {
    const float t = sm[tid][0] + sm[tid][1] + sm[tid][2] + sm[tid][3];
    const int zz = (item0 + tid) >> 13;
    float val = zz ? logf(t) : log1pf(t);
#pragma unroll
    for (int m = 1; m < 64; m <<= 1) val += __shfl_xor(val, m);
    if (tid == 0) atomicAdd(out, val * (1.0f / (float)N));
  }
}

extern "C" void kernel_launch(void* const* d_in, const int* in_sizes, int n_in,
                              void* d_out, int out_size, void* d_ws, size_t ws_size,
                              hipStream_t stream) {
  const float* e = (const float*)d_in[0];
  const float* p = (const float*)d_in[1];
  const float* n = (const float*)d_in[2];

  char* w = (char*)d_ws;
  uint8_t* eb = (uint8_t*)w;                                     // 2 MB
  uint8_t* pb = eb + (size_t)N * D;                              // 2 MB
  uint8_t* nb = pb + (size_t)N * D;                              // 2 MB
  float* cbuf = (float*)(nb + (size_t)N * D);                    // 32 KB
  float* part = cbuf + N;                                        // 2*64*8192*4 = 4 MB
  float* out = (float*)d_out;

  normalize_kernel<<<N / 4, 256, 0, stream>>>(e, p, n, (uint32_t*)eb, (uint32_t*)pb,
                                              (uint32_t*)nb, cbuf, out);
  simexp_kernel<<<dim3(N / BM, N / BN, 2), 256, 0, stream>>>(eb, pb, nb, cbuf, part);
  reduce_kernel<<<256, 256, 0, stream>>>(part, out);
}

// Round 7
// 150.445 us; speedup vs baseline: 9.1941x; 9.1941x over previous
//
#include <hip/hip_runtime.h>
#include <stdint.h>

#define N 8192
#define D 256          // elements per row == bytes per fp8 row
#define INV_T 20.0f
#define BM 128
#define BN 128
#define BK 64
#define NXB 64         // col-blocks (N/BN)

typedef __attribute__((ext_vector_type(16))) float f32x16;
typedef __attribute__((ext_vector_type(2))) long i64x2;

typedef __attribute__((address_space(3))) uint32_t lds_u32;
typedef __attribute__((address_space(1))) const uint32_t gbl_u32;

// Kernel 1: per-row fp32 normalize -> fp8 e4m3 (OCP) copies; c[i]=(e_i.p_i)/T exact fp32.
// Also zeroes out[0] (poisoned 0xAA; reduce kernel atomicAdds into it).
__global__ __launch_bounds__(256) void normalize_kernel(
    const float* __restrict__ e, const float* __restrict__ p, const float* __restrict__ n,
    uint32_t* __restrict__ eb, uint32_t* __restrict__ pb, uint32_t* __restrict__ nb,
    float* __restrict__ cbuf, float* __restrict__ out0) {
  const int tid = threadIdx.x;
  const int wave = tid >> 6, lane = tid & 63;
  const int row = blockIdx.x * 4 + wave;          // one wave per row
  if (blockIdx.x == 0 && tid == 0) out0[0] = 0.0f;

  const float4 ev = ((const float4*)(e + (size_t)row * D))[lane];
  const float4 pv = ((const float4*)(p + (size_t)row * D))[lane];
  const float4 nv = ((const float4*)(n + (size_t)row * D))[lane];

  float sse = ev.x*ev.x + ev.y*ev.y + ev.z*ev.z + ev.w*ev.w;
  float ssp = pv.x*pv.x + pv.y*pv.y + pv.z*pv.z + pv.w*pv.w;
  float ssn = nv.x*nv.x + nv.y*nv.y + nv.z*nv.z + nv.w*nv.w;
  float dep = ev.x*pv.x + ev.y*pv.y + ev.z*pv.z + ev.w*pv.w;
#pragma unroll
  for (int m = 1; m < 64; m <<= 1) {
    sse += __shfl_xor(sse, m);
    ssp += __shfl_xor(ssp, m);
    ssn += __shfl_xor(ssn, m);
    dep += __shfl_xor(dep, m);
  }
  const float se = 1.0f / fmaxf(sqrtf(sse), 1e-8f);
  const float sp = 1.0f / fmaxf(sqrtf(ssp), 1e-8f);
  const float sn = 1.0f / fmaxf(sqrtf(ssn), 1e-8f);

  int ue = __builtin_amdgcn_cvt_pk_fp8_f32(ev.x*se, ev.y*se, 0, false);
  ue     = __builtin_amdgcn_cvt_pk_fp8_f32(ev.z*se, ev.w*se, ue, true);
  int up = __builtin_amdgcn_cvt_pk_fp8_f32(pv.x*sp, pv.y*sp, 0, false);
  up     = __builtin_amdgcn_cvt_pk_fp8_f32(pv.z*sp, pv.w*sp, up, true);
  int un = __builtin_amdgcn_cvt_pk_fp8_f32(nv.x*sn, nv.y*sn, 0, false);
  un     = __builtin_amdgcn_cvt_pk_fp8_f32(nv.z*sn, nv.w*sn, un, true);
  eb[row * 64 + lane] = (uint32_t)ue;
  pb[row * 64 + lane] = (uint32_t)up;
  nb[row * 64 + lane] = (uint32_t)un;

  if (lane == 0) cbuf[row] = dep * se * sp * INV_T;
}

// Kernel 2: 128x128-tile fp8 GEMM (X @ Y^T), 32x32x16_fp8_fp8 MFMA, fused exp row-sums.
// Round-3 structure with DOUBLE-BUFFERED staging: one barrier per k-iter; stage(k+1)
// is issued AFTER the barrier and flies during compute(k), so the forced vmcnt(0)
// at the next barrier drains loads that are already ~a full compute phase old.
// LDS 2x(8+8)KB + 0.5KB = 33KB -> 4 blocks/CU (launch_bounds(256,4): 128-reg budget,
// acc 64 + ~48 working regs fits -- the hard-learned cap from rounds 5/6).
// Swizzle: 16B-group gg of row r at slot gg ^ ((r>>1)&3); storage-only K-permutation
// applied identically to A and B.
__global__ __launch_bounds__(256, 4) void simexp_kernel(
    const uint8_t* __restrict__ eb, const uint8_t* __restrict__ pb,
    const uint8_t* __restrict__ nb, const float* __restrict__ cbuf,
    float* __restrict__ part) {
  __shared__ uint8_t As[2][BM * BK];   // 2 x 8 KB
  __shared__ uint8_t Bs[2][BN * BK];   // 2 x 8 KB
  __shared__ float cs[BM];             // 512 B

  const int z = blockIdx.z;
  const uint8_t* __restrict__ A = z ? pb : eb;
  const uint8_t* __restrict__ B = z ? eb : nb;

  const int tid = threadIdx.x;
  const int wave = tid >> 6, lane = tid & 63;
  const int lane31 = lane & 31, half = lane >> 5;
  const int rowTile = blockIdx.x * BM, colblk = blockIdx.y;
  const int colTile = colblk * BN;
  const int rl = wave * 32 + lane31;              // this lane's A row (local)

  if (tid < BM) cs[tid] = cbuf[rowTile + tid];

  // Per-thread staging geometry (fixed across k-iters).
  const int c0 = tid, c1 = 256 + tid;             // the two 16B-chunks this thread stages
  const int r0 = c0 >> 2, gg0 = (c0 & 3) ^ ((r0 >> 1) & 3);
  const int r1 = c1 >> 2, gg1 = (c1 & 3) ^ ((r1 >> 1) & 3);
  const uint8_t* ga0 = A + (size_t)(rowTile + r0) * D + gg0 * 16;
  const uint8_t* ga1 = A + (size_t)(rowTile + r1) * D + gg1 * 16;
  const uint8_t* gb0 = B + (size_t)(colTile + r0) * D + gg0 * 16;
  const uint8_t* gb1 = B + (size_t)(colTile + r1) * D + gg1 * 16;

  f32x16 acc[4];
#pragma unroll
  for (int ni = 0; ni < 4; ++ni)
#pragma unroll
    for (int r = 0; r < 16; ++r) acc[ni][r] = 0.0f;

  // Prologue: stage k-iter 0 into buffer 0.
  __builtin_amdgcn_global_load_lds((gbl_u32*)ga0, (lds_u32*)&As[0][c0 * 16], 16, 0, 0);
  __builtin_amdgcn_global_load_lds((gbl_u32*)ga1, (lds_u32*)&As[0][c1 * 16], 16, 0, 0);
  __builtin_amdgcn_global_load_lds((gbl_u32*)gb0, (lds_u32*)&Bs[0][c0 * 16], 16, 0, 0);
  __builtin_amdgcn_global_load_lds((gbl_u32*)gb1, (lds_u32*)&Bs[0][c1 * 16], 16, 0, 0);

#pragma unroll
  for (int k0i = 0; k0i < 4; ++k0i) {
    const int buf = k0i & 1;
    __syncthreads();   // drains stage(k0i); also guards buf reuse + publishes cs
    if (k0i < 3) {
      const int nb_ = buf ^ 1;
      const int k1 = (k0i + 1) * BK;
      __builtin_amdgcn_global_load_lds((gbl_u32*)(ga0 + k1), (lds_u32*)&As[nb_][c0 * 16], 16, 0, 0);
      __builtin_amdgcn_global_load_lds((gbl_u32*)(ga1 + k1), (lds_u32*)&As[nb_][c1 * 16], 16, 0, 0);
      __builtin_amdgcn_global_load_lds((gbl_u32*)(gb0 + k1), (lds_u32*)&Bs[nb_][c0 * 16], 16, 0, 0);
      __builtin_amdgcn_global_load_lds((gbl_u32*)(gb1 + k1), (lds_u32*)&Bs[nb_][c1 * 16], 16, 0, 0);
    }

#pragma unroll
    for (int g = 0; g < 2; ++g) {
      const int gga = half * 2 + g;               // this lane's logical 16B-group
      const i64x2 av = *(const i64x2*)&As[buf][rl * BK + ((gga ^ ((rl >> 1) & 3)) * 16)];
      i64x2 bv[4];
#pragma unroll
      for (int ni = 0; ni < 4; ++ni) {
        const int cl = ni * 32 + lane31;
        bv[ni] = *(const i64x2*)&Bs[buf][cl * BK + ((gga ^ ((cl >> 1) & 3)) * 16)];
      }
#pragma unroll
      for (int ni = 0; ni < 4; ++ni)
        acc[ni] = __builtin_amdgcn_mfma_f32_32x32x16_fp8_fp8(av.x, bv[ni].x, acc[ni], 0, 0, 0);
#pragma unroll
      for (int ni = 0; ni < 4; ++ni)
        acc[ni] = __builtin_amdgcn_mfma_f32_32x32x16_fp8_fp8(av.y, bv[ni].y, acc[ni], 0, 0, 0);
    }
  }

  // Epilogue. 32x32 C/D: col=lane&31, row=(reg&3)+8*(reg>>2)+4*half (m74/m101).
#pragma unroll
  for (int reg = 0; reg < 16; ++reg) {
    const int rlocal = (reg & 3) + 8 * (reg >> 2) + 4 * half;
    const int rowl = wave * 32 + rlocal;
    const float cv = cs[rowl];
    float v = 0.0f;
#pragma unroll
    for (int ni = 0; ni < 4; ++ni)
      v += __expf(acc[ni][reg] * INV_T - cv);
    v += __shfl_xor(v, 1);
    v += __shfl_xor(v, 2);
    v += __shfl_xor(v, 4);
    v += __shfl_xor(v, 8);
    v += __shfl_xor(v, 16);
    if (lane31 == 0)
      part[((size_t)(z * NXB + colblk)) * N + rowTile + rowl] = v;
  }
}

// Kernel 3: per-row sum of 64 partials -> log/log1p -> block reduce -> atomicAdd(out).
// 256 blocks; block handles 64 row-items; (tid&63)=item, (tid>>6)=quarter of x-range.
__global__ __launch_bounds__(256) void reduce_kernel(const float* __restrict__ part,
                                                     float* __restrict__ out) {
  __shared__ float sm[64][4];
  const int tid = threadIdx.x;
  const int item0 = blockIdx.x * 64;               // items: z*N + row, 16384 total
  const int il = tid & 63, seg = tid >> 6;
  const int item = item0 + il;
  const int z = item >> 13, row = item & (N - 1);
  float s = 0.0f;
#pragma unroll
  for (int x = seg * 16; x < seg * 16 + 16; ++x)
    s += part[((size_t)(z * NXB + x)) * N + row];
  sm[il][seg] = s;
  __syncthreads();
  if (tid < 64) {
    const float t = sm[tid][0] + sm[tid][1] + sm[tid][2] + sm[tid][3];
    const int zz = (item0 + tid) >> 13;
    float val = zz ? logf(t) : log1pf(t);
#pragma unroll
    for (int m = 1; m < 64; m <<= 1) val += __shfl_xor(val, m);
    if (tid == 0) atomicAdd(out, val * (1.0f / (float)N));
  }
}

extern "C" void kernel_launch(void* const* d_in, const int* in_sizes, int n_in,
                              void* d_out, int out_size, void* d_ws, size_t ws_size,
                              hipStream_t stream) {
  const float* e = (const float*)d_in[0];
  const float* p = (const float*)d_in[1];
  const float* n = (const float*)d_in[2];

  char* w = (char*)d_ws;
  uint8_t* eb = (uint8_t*)w;                                     // 2 MB
  uint8_t* pb = eb + (size_t)N * D;                              // 2 MB
  uint8_t* nb = pb + (size_t)N * D;                              // 2 MB
  float* cbuf = (float*)(nb + (size_t)N * D);                    // 32 KB
  float* part = cbuf + N;                                        // 2*64*8192*4 = 4 MB
  float* out = (float*)d_out;

  normalize_kernel<<<N / 4, 256, 0, stream>>>(e, p, n, (uint32_t*)eb, (uint32_t*)pb,
                                              (uint32_t*)nb, cbuf, out);
  simexp_kernel<<<dim3(N / BM, N / BN, 2), 256, 0, stream>>>(eb, pb, nb, cbuf, part);
  reduce_kernel<<<256, 256, 0, stream>>>(part, out);
}